// Round 2
// baseline (1496.362 us; speedup 1.0000x reference)
//
#include <hip/hip_runtime.h>

#define B_ 16
#define L_ 512
#define D_ 768
#define H_ 4
#define A_ 100
#define DK_ 25
#define P_ 3
#define XP_ 128   // padded row stride for x/x1/x2/axb

// ------------------------------------------------- K0: wT[d][a] = Wxx_w[a][d], pad a to 128
__global__ __launch_bounds__(256) void k_wprep(const float* __restrict__ Wxx_w,
                                               float* __restrict__ wT)
{
    const int idx = blockIdx.x * 256 + threadIdx.x;     // 768*128
    const int d = idx >> 7, a = idx & 127;
    wT[idx] = (a < A_) ? Wxx_w[(size_t)a * D_ + d] : 0.f;
}

// ------------------------------------- K0b: aggT[c][k][n] = agg_w[n][c*100+k], pad n to 128
__global__ __launch_bounds__(256) void k_aggprep(const float* __restrict__ agg_w,
                                                 float* __restrict__ aggT)
{
    const int idx = blockIdx.x * 256 + threadIdx.x;     // 3*100*128 = 38400
    const int n = idx & 127, k = (idx >> 7) % A_, c = idx / (128 * A_);
    aggT[idx] = (n < A_) ? agg_w[(size_t)n * (3 * A_) + c * A_ + k] : 0.f;
}

// ------------------------------------- K0c: qkT[k][n]: n<128 -> q_w[n][k], n>=128 -> k_w[n-128][k]
__global__ __launch_bounds__(256) void k_qkprep(const float* __restrict__ q_w,
                                                const float* __restrict__ k_w,
                                                float* __restrict__ qkT)
{
    const int idx = blockIdx.x * 256 + threadIdx.x;     // 100*256 = 25600
    const int n = idx & 255, k = idx >> 8;
    const int half = n >> 7, a = n & 127;
    const float* w = half ? k_w : q_w;
    qkT[idx] = (a < A_) ? w[(size_t)a * A_ + k] : 0.f;
}

// ------------------------------------- K0d: WT[k][n] = W_w[n][k], pad n to 128
__global__ __launch_bounds__(256) void k_wprep2(const float* __restrict__ W_w,
                                                float* __restrict__ WT)
{
    const int idx = blockIdx.x * 256 + threadIdx.x;     // 100*128 = 12800
    const int n = idx & 127, k = idx >> 7;
    WT[idx] = (n < A_) ? W_w[(size_t)n * A_ + k] : 0.f;
}

// ------------------- K1: fused LayerNorm + x = seq_ln @ Wxx^T + b  (tiled GEMM)
// output xp: (B*L, 128), cols 100..127 zero.
__global__ __launch_bounds__(256) void k_lnx(
    const float* __restrict__ seq, const float* __restrict__ ln_a, const float* __restrict__ ln_b,
    const float* __restrict__ wT, const float* __restrict__ Wxx_b, float* __restrict__ xp)
{
    __shared__ float ss[32][36];
    __shared__ float ws[32][128];
    __shared__ float mean_s[32], rd_s[32];
    const int tid = threadIdx.x;
    const int row0 = blockIdx.x * 32;
    const int wv = tid >> 6, lane = tid & 63;

    for (int rr = 0; rr < 8; ++rr) {
        const int r = wv * 8 + rr;
        const float4* src = (const float4*)(seq + (size_t)(row0 + r) * D_);
        float4 a = src[lane], b = src[lane + 64], c = src[lane + 128];
        float s = a.x + a.y + a.z + a.w + b.x + b.y + b.z + b.w + c.x + c.y + c.z + c.w;
        #pragma unroll
        for (int o = 32; o; o >>= 1) s += __shfl_xor(s, o);
        const float m = s * (1.0f / 768.0f);
        float q = (a.x-m)*(a.x-m) + (a.y-m)*(a.y-m) + (a.z-m)*(a.z-m) + (a.w-m)*(a.w-m)
                + (b.x-m)*(b.x-m) + (b.y-m)*(b.y-m) + (b.z-m)*(b.z-m) + (b.w-m)*(b.w-m)
                + (c.x-m)*(c.x-m) + (c.y-m)*(c.y-m) + (c.z-m)*(c.z-m) + (c.w-m)*(c.w-m);
        #pragma unroll
        for (int o = 32; o; o >>= 1) q += __shfl_xor(q, o);
        if (lane == 0) {
            mean_s[r] = m;
            rd_s[r] = 1.0f / (sqrtf(q * (1.0f / 767.0f)) + 1e-6f);
        }
    }
    __syncthreads();

    const int c4 = tid & 31, rg = tid >> 5;
    float4 acc[4];
    #pragma unroll
    for (int i = 0; i < 4; ++i) { acc[i].x = acc[i].y = acc[i].z = acc[i].w = 0.f; }

    for (int kc = 0; kc < 24; ++kc) {
        {
            const int r = tid >> 3, k4 = tid & 7;
            float4 v = *(const float4*)(seq + (size_t)(row0 + r) * D_ + kc * 32 + k4 * 4);
            float4 la = ((const float4*)ln_a)[kc * 8 + k4];
            float4 lb = ((const float4*)ln_b)[kc * 8 + k4];
            const float m = mean_s[r], rd = rd_s[r];
            float4 o;
            o.x = la.x * ((v.x - m) * rd) + lb.x;
            o.y = la.y * ((v.y - m) * rd) + lb.y;
            o.z = la.z * ((v.z - m) * rd) + lb.z;
            o.w = la.w * ((v.w - m) * rd) + lb.w;
            *(float4*)&ss[r][k4 * 4] = o;
        }
        #pragma unroll
        for (int t = 0; t < 4; ++t) {
            const int idx = tid + t * 256;
            const int k = idx >> 5, cc = idx & 31;
            *(float4*)&ws[k][cc * 4] = *(const float4*)(wT + (size_t)(kc * 32 + k) * 128 + cc * 4);
        }
        __syncthreads();
        #pragma unroll 2
        for (int k = 0; k < 32; k += 4) {
            float4 sv[4];
            #pragma unroll
            for (int i = 0; i < 4; ++i) sv[i] = *(float4*)&ss[rg * 4 + i][k];
            #pragma unroll
            for (int j = 0; j < 4; ++j) {
                float4 w4 = *(float4*)&ws[k + j][c4 * 4];
                #pragma unroll
                for (int i = 0; i < 4; ++i) {
                    const float sj = ((float*)&sv[i])[j];
                    acc[i].x += sj * w4.x; acc[i].y += sj * w4.y;
                    acc[i].z += sj * w4.z; acc[i].w += sj * w4.w;
                }
            }
        }
        __syncthreads();
    }

    float4 bias = {0.f, 0.f, 0.f, 0.f};
    if (c4 < 25) bias = ((const float4*)Wxx_b)[c4];
    #pragma unroll
    for (int i = 0; i < 4; ++i) {
        float4 o;
        o.x = acc[i].x + bias.x; o.y = acc[i].y + bias.y;
        o.z = acc[i].z + bias.z; o.w = acc[i].w + bias.w;
        *(float4*)(xp + (size_t)(row0 + rg * 4 + i) * XP_ + c4 * 4) = o;   // pad cols stay 0 (wT padded)
    }
}

// ------------------- K2: q/k = x @ [q_w|k_w]^T + bias  (tiled GEMM); qt/kt (B,L,100)
__global__ __launch_bounds__(256) void k_qkg(
    const float* __restrict__ xp, const float* __restrict__ qkT,
    const float* __restrict__ q_b, const float* __restrict__ k_b,
    float* __restrict__ qt, float* __restrict__ kt)
{
    __shared__ float ss[32][104];
    __shared__ float ws[A_][128];
    const int tid = threadIdx.x;
    const int row0 = blockIdx.x * 32;
    const int half = blockIdx.y;
    const int c4 = tid & 31, rg = tid >> 5;

    for (int idx = tid; idx < 32 * 25; idx += 256) {
        const int r = idx / 25, k4 = idx % 25;
        *(float4*)&ss[r][k4 * 4] = *(const float4*)(xp + (size_t)(row0 + r) * XP_ + k4 * 4);
    }
    for (int idx = tid; idx < A_ * 32; idx += 256) {
        const int k = idx >> 5, cc = idx & 31;
        *(float4*)&ws[k][cc * 4] = *(const float4*)(qkT + (size_t)k * 256 + half * 128 + cc * 4);
    }
    __syncthreads();

    float4 acc[4];
    #pragma unroll
    for (int i = 0; i < 4; ++i) { acc[i].x = acc[i].y = acc[i].z = acc[i].w = 0.f; }
    #pragma unroll 5
    for (int k = 0; k < A_; k += 4) {
        float4 sv[4];
        #pragma unroll
        for (int i = 0; i < 4; ++i) sv[i] = *(float4*)&ss[rg * 4 + i][k];
        #pragma unroll
        for (int j = 0; j < 4; ++j) {
            float4 w4 = *(float4*)&ws[k + j][c4 * 4];
            #pragma unroll
            for (int i = 0; i < 4; ++i) {
                const float sj = ((float*)&sv[i])[j];
                acc[i].x += sj * w4.x; acc[i].y += sj * w4.y;
                acc[i].z += sj * w4.z; acc[i].w += sj * w4.w;
            }
        }
    }

    if (c4 < 25) {
        const float4 bias = ((const float4*)(half ? k_b : q_b))[c4];
        float* dst = half ? kt : qt;
        #pragma unroll
        for (int i = 0; i < 4; ++i) {
            float4 o;
            o.x = acc[i].x + bias.x; o.y = acc[i].y + bias.y;
            o.z = acc[i].z + bias.z; o.w = acc[i].w + bias.w;
            *(float4*)(dst + (size_t)(row0 + rg * 4 + i) * A_ + c4 * 4) = o;
        }
    }
}

// --------------- K3 (fused v2): scores(QK^T,mask,syn) + softmax + h-combine.
// Writes ONLY es plane (b,0) = sum_h adj[h] and es plane (b,1) = sum_h cs[h]*adj[h].
// Block = (b, 8 q-rows); wave wv owns q-rows {2wv, 2wv+1} for ALL 4 heads, so the
// h-combine is in-lane (no LDS ps buffer, no spills). Each lane holds j = t*64+lane,
// t=0..7: p[h][i_loc][t] = 64 regs. K staged per 64-row tile, stride 101 floats
// (bank = 5*lane mod 32: conflict-free). LDS total ~29.5 KB -> 4-5 blocks/CU.
#define NI_ 8
__global__ __launch_bounds__(256) void k_attn(
    const float* __restrict__ qt, const float* __restrict__ kt,
    const float* __restrict__ syn, const int* __restrict__ src_mask,
    const float* __restrict__ Wx_w, float* __restrict__ es)
{
    __shared__ __align__(16) float ks[64 * 101];        // 25856 B
    __shared__ __align__(16) float qs[NI_ * 4 * 28];    // [i][h][d], 3584 B
    __shared__ float cs[4];

    const int tid = threadIdx.x;
    const int b = blockIdx.y;
    const int i0 = blockIdx.x * NI_;
    const int wv = tid >> 6, lane = tid & 63;

    // stage q fragments: qs[(i*4+h)*28 + d]
    for (int idx = tid; idx < NI_ * 4 * 25; idx += 256) {
        const int i = idx / 100, rem = idx % 100;
        const int h = rem / 25, d = rem % 25;
        qs[(i * 4 + h) * 28 + d] = qt[(size_t)(b * L_ + i0 + i) * A_ + h * DK_ + d];
    }
    if (tid < 4) cs[tid] = Wx_w[tid] + Wx_w[204 + tid] + Wx_w[408 + tid] + Wx_w[612 + tid];

    float p[4][2][8];   // [h][i_loc][t]
    #pragma unroll
    for (int h = 0; h < 4; ++h)
        #pragma unroll
        for (int il = 0; il < 2; ++il)
            #pragma unroll
            for (int t = 0; t < 8; ++t) p[h][il][t] = 0.f;

    #pragma unroll
    for (int t = 0; t < 8; ++t) {
        __syncthreads();    // t=0: qs/cs staged; t>0: prev tile reads done
        // stage K rows [t*64, t*64+64), 100 cols, row stride 101
        for (int idx = tid; idx < 64 * 25; idx += 256) {
            const int r = idx / 25, c = idx % 25;
            const float4 v = *(const float4*)(kt + (size_t)(b * L_ + t * 64 + r) * A_ + c * 4);
            float* dst = ks + r * 101 + c * 4;
            dst[0] = v.x; dst[1] = v.y; dst[2] = v.z; dst[3] = v.w;
        }
        __syncthreads();
        // compute: this tile fully produces scores for j = t*64 + lane
        const float* kr = ks + lane * 101;
        #pragma unroll
        for (int h = 0; h < 4; ++h) {
            const float* kh = kr + h * DK_;
            const float* q0 = qs + ((wv * 2 + 0) * 4 + h) * 28;
            const float* q1 = qs + ((wv * 2 + 1) * 4 + h) * 28;
            float a0 = 0.f, a1 = 0.f;
            #pragma unroll
            for (int d4 = 0; d4 < 6; ++d4) {
                const float k0 = kh[d4 * 4 + 0], k1 = kh[d4 * 4 + 1];
                const float k2 = kh[d4 * 4 + 2], k3 = kh[d4 * 4 + 3];
                const float4 qa = *(const float4*)&q0[d4 * 4];
                const float4 qb = *(const float4*)&q1[d4 * 4];
                a0 += qa.x * k0 + qa.y * k1 + qa.z * k2 + qa.w * k3;
                a1 += qb.x * k0 + qb.y * k1 + qb.z * k2 + qb.w * k3;
            }
            {
                const float kk = kh[24];
                a0 += q0[24] * kk;
                a1 += q1[24] * kk;
            }
            p[h][0][t] = a0;
            p[h][1][t] = a1;
        }
    }

    int m[8];
    #pragma unroll
    for (int t = 0; t < 8; ++t) m[t] = src_mask[b * L_ + t * 64 + lane];

    const int ig0 = i0 + wv * 2;
    const float c0 = cs[0], c1 = cs[1], c2 = cs[2], c3 = cs[3];
    #pragma unroll
    for (int il = 0; il < 2; ++il) {
        const int ig = ig0 + il;
        #pragma unroll
        for (int h = 0; h < 4; ++h) {
            const float* sy = syn + ((size_t)(b * H_ + h) * L_ + ig) * L_;
            float s[8];
            float mx = -3.0e38f;
            #pragma unroll
            for (int t = 0; t < 8; ++t) {
                s[t] = (m[t] ? p[h][il][t] * 0.2f : -1e9f) + sy[t * 64 + lane];
                mx = fmaxf(mx, s[t]);
            }
            #pragma unroll
            for (int o = 32; o; o >>= 1) mx = fmaxf(mx, __shfl_xor(mx, o));
            float sum = 0.f;
            #pragma unroll
            for (int t = 0; t < 8; ++t) { s[t] = __expf(s[t] - mx); sum += s[t]; }
            #pragma unroll
            for (int o = 32; o; o >>= 1) sum += __shfl_xor(sum, o);
            const float inv = 1.0f / sum;
            #pragma unroll
            for (int t = 0; t < 8; ++t) p[h][il][t] = s[t] * inv;   // overwrite: normalized probs
        }
        float* e0 = es + ((size_t)(b * H_ + 0) * L_ + ig) * L_;
        float* e1 = es + ((size_t)(b * H_ + 1) * L_ + ig) * L_;
        #pragma unroll
        for (int t = 0; t < 8; ++t) {
            const float p0 = p[0][il][t], p1 = p[1][il][t], p2 = p[2][il][t], p3 = p[3][il][t];
            e0[t * 64 + lane] = p0 + p1 + p2 + p3;
            e1[t * 64 + lane] = c0 * p0 + c1 * p1 + c2 * p2 + c3 * p3;
        }
    }
}

// ------------- K4a: axb = (adj @ x)/H [+ extras]   (tiled GEMM, 32 rows x 128 cols, K=512)
template<int LAYER2>
__global__ __launch_bounds__(256) void k_axg(
    const float* __restrict__ adj, const float* __restrict__ xp,
    const float* __restrict__ S, const float* __restrict__ T,
    const float* __restrict__ Vv, const float* __restrict__ Wx_b,
    float* __restrict__ axb)
{
    __shared__ float ss[32][36];
    __shared__ float ws[32][128];
    const int tid = threadIdx.x;
    const int row0 = blockIdx.x * 32;       // global row in [0, B*L)
    const int b = row0 >> 9, i0 = row0 & 511;
    const float* adjb = adj + (size_t)b * 4 * L_ * L_;
    const int c4 = tid & 31, rg = tid >> 5;
    float4 acc[4];
    #pragma unroll
    for (int i = 0; i < 4; ++i) { acc[i].x = acc[i].y = acc[i].z = acc[i].w = 0.f; }

    for (int kc = 0; kc < 16; ++kc) {
        {
            const int r = tid >> 3, q4 = tid & 7;
            *(float4*)&ss[r][q4 * 4] =
                *(const float4*)(adjb + (size_t)(i0 + r) * L_ + kc * 32 + q4 * 4);
        }
        #pragma unroll
        for (int t = 0; t < 4; ++t) {
            const int idx = tid + t * 256;
            const int k = idx >> 5, cc = idx & 31;
            *(float4*)&ws[k][cc * 4] =
                *(const float4*)(xp + ((size_t)b * L_ + kc * 32 + k) * XP_ + cc * 4);
        }
        __syncthreads();
        #pragma unroll 2
        for (int k = 0; k < 32; k += 4) {
            float4 sv[4];
            #pragma unroll
            for (int i = 0; i < 4; ++i) sv[i] = *(float4*)&ss[rg * 4 + i][k];
            #pragma unroll
            for (int j = 0; j < 4; ++j) {
                float4 w4 = *(float4*)&ws[k + j][c4 * 4];
                #pragma unroll
                for (int i = 0; i < 4; ++i) {
                    const float sj = ((float*)&sv[i])[j];
                    acc[i].x += sj * w4.x; acc[i].y += sj * w4.y;
                    acc[i].z += sj * w4.z; acc[i].w += sj * w4.w;
                }
            }
        }
        __syncthreads();
    }

    float wb = 0.f;
    float4 Sv = {0.f, 0.f, 0.f, 0.f}, Tv = {0.f, 0.f, 0.f, 0.f};
    if (LAYER2) {
        wb = Wx_b[0] + Wx_b[1] + Wx_b[2] + Wx_b[3];
        if (c4 < 25) {
            Sv = ((const float4*)(S + b * A_))[c4];
            Tv = ((const float4*)(T + b * A_))[c4];
        }
    }
    #pragma unroll
    for (int i = 0; i < 4; ++i) {
        const int grow = row0 + rg * 4 + i;
        const float vv = LAYER2 ? (Vv[grow] + wb) : 0.f;
        float4 o;
        o.x = (acc[i].x + Sv.x + vv * Tv.x) * 0.25f;
        o.y = (acc[i].y + Sv.y + vv * Tv.y) * 0.25f;
        o.z = (acc[i].z + Sv.z + vv * Tv.z) * 0.25f;
        o.w = (acc[i].w + Sv.w + vv * Tv.w) * 0.25f;
        *(float4*)(axb + (size_t)grow * XP_ + c4 * 4) = o;   // pad cols -> 0
    }
}

// ------------- K4b: xout = relu(axb @ W^T + b)   (tiled GEMM, K=100)
__global__ __launch_bounds__(256) void k_xw(
    const float* __restrict__ axb, const float* __restrict__ WT,
    const float* __restrict__ W_b, float* __restrict__ xout)
{
    __shared__ float ss[32][104];
    __shared__ float ws[A_][128];
    const int tid = threadIdx.x;
    const int row0 = blockIdx.x * 32;
    const int c4 = tid & 31, rg = tid >> 5;

    for (int idx = tid; idx < 32 * 25; idx += 256) {
        const int r = idx / 25, k4 = idx % 25;
        *(float4*)&ss[r][k4 * 4] = *(const float4*)(axb + (size_t)(row0 + r) * XP_ + k4 * 4);
    }
    for (int idx = tid; idx < A_ * 32; idx += 256) {
        const int k = idx >> 5, cc = idx & 31;
        *(float4*)&ws[k][cc * 4] = *(const float4*)(WT + (size_t)k * 128 + cc * 4);
    }
    __syncthreads();

    float4 acc[4];
    #pragma unroll
    for (int i = 0; i < 4; ++i) { acc[i].x = acc[i].y = acc[i].z = acc[i].w = 0.f; }
    #pragma unroll 5
    for (int k = 0; k < A_; k += 4) {
        float4 sv[4];
        #pragma unroll
        for (int i = 0; i < 4; ++i) sv[i] = *(float4*)&ss[rg * 4 + i][k];
        #pragma unroll
        for (int j = 0; j < 4; ++j) {
            float4 w4 = *(float4*)&ws[k + j][c4 * 4];
            #pragma unroll
            for (int i = 0; i < 4; ++i) {
                const float sj = ((float*)&sv[i])[j];
                acc[i].x += sj * w4.x; acc[i].y += sj * w4.y;
                acc[i].z += sj * w4.z; acc[i].w += sj * w4.w;
            }
        }
    }

    float4 bias = {0.f, 0.f, 0.f, 0.f};
    if (c4 < 25) bias = ((const float4*)W_b)[c4];
    #pragma unroll
    for (int i = 0; i < 4; ++i) {
        float4 o;
        o.x = fmaxf(acc[i].x + bias.x, 0.f); o.y = fmaxf(acc[i].y + bias.y, 0.f);
        o.z = fmaxf(acc[i].z + bias.z, 0.f); o.w = fmaxf(acc[i].w + bias.w, 0.f);
        *(float4*)(xout + (size_t)(row0 + rg * 4 + i) * XP_ + c4 * 4) = o;  // WT pad -> 0
    }
}

// ---------------- K5: rank-1 extras for layer 2: Vv (B,L), T,S (B,A); zero pooled
__global__ __launch_bounds__(256) void k_extras(
    const float* __restrict__ x1, const float* __restrict__ Wx_w,
    float* __restrict__ Vv, float* __restrict__ T, float* __restrict__ S,
    float* __restrict__ pooled)
{
    __shared__ float b1s[A_], b2s[A_], Ul[L_];
    const int tid = threadIdx.x, b = blockIdx.x;
    if (tid < A_) {
        float s1 = 0.f, s2 = 0.f;
        #pragma unroll
        for (int g = 0; g < H_; ++g) {
            s1 += Wx_w[g * 204 + 4 + tid];
            s2 += Wx_w[g * 204 + 104 + tid];
        }
        b1s[tid] = s1; b2s[tid] = s2;
        pooled[b * A_ + tid] = 0.f;
    }
    __syncthreads();
    for (int j = tid; j < L_; j += 256) {
        const float* xr = x1 + ((size_t)b * L_ + j) * XP_;
        float u = 0.f, v = 0.f;
        #pragma unroll 4
        for (int c = 0; c < A_; ++c) { float xv = xr[c]; u += xv * b1s[c]; v += xv * b2s[c]; }
        Ul[j] = u;
        Vv[b * L_ + j] = v;
    }
    __syncthreads();
    if (tid < A_) {
        float t = 0.f, s = 0.f;
        for (int j = 0; j < L_; ++j) {
            float xv = x1[((size_t)b * L_ + j) * XP_ + tid];
            t += xv; s += Ul[j] * xv;
        }
        T[b * A_ + tid] = t; S[b * A_ + tid] = s;
    }
}

// ---------------- K6: pooled[b] += sum_rows relu([x,x1,x2]@agg^T + b)   (tiled GEMM)
__global__ __launch_bounds__(256) void k_nodepool(
    const float* __restrict__ x, const float* __restrict__ x1, const float* __restrict__ x2,
    const float* __restrict__ aggT, const float* __restrict__ agg_b,
    float* __restrict__ pooled)
{
    __shared__ float ss[32][104];
    __shared__ float ws[A_][128];
    const int tid = threadIdx.x;
    const int row0 = blockIdx.x * 32;
    const int b = row0 >> 9;
    const int c4 = tid & 31, rg = tid >> 5;
    float4 acc[4];
    #pragma unroll
    for (int i = 0; i < 4; ++i) { acc[i].x = acc[i].y = acc[i].z = acc[i].w = 0.f; }

    for (int c = 0; c < 3; ++c) {
        const float* src = (c == 0) ? x : (c == 1) ? x1 : x2;
        for (int idx = tid; idx < 32 * 25; idx += 256) {
            const int r = idx / 25, k4 = idx % 25;
            *(float4*)&ss[r][k4 * 4] =
                *(const float4*)(src + (size_t)(row0 + r) * XP_ + k4 * 4);
        }
        for (int idx = tid; idx < A_ * 32; idx += 256) {
            const int k = idx >> 5, cc = idx & 31;
            *(float4*)&ws[k][cc * 4] =
                *(const float4*)(aggT + ((size_t)c * A_ + k) * 128 + cc * 4);
        }
        __syncthreads();
        #pragma unroll 5
        for (int k = 0; k < A_; k += 4) {
            float4 sv[4];
            #pragma unroll
            for (int i = 0; i < 4; ++i) sv[i] = *(float4*)&ss[rg * 4 + i][k];
            #pragma unroll
            for (int j = 0; j < 4; ++j) {
                float4 w4 = *(float4*)&ws[k + j][c4 * 4];
                #pragma unroll
                for (int i = 0; i < 4; ++i) {
                    const float sj = ((float*)&sv[i])[j];
                    acc[i].x += sj * w4.x; acc[i].y += sj * w4.y;
                    acc[i].z += sj * w4.z; acc[i].w += sj * w4.w;
                }
            }
        }
        __syncthreads();
    }

    float4 bias = {0.f, 0.f, 0.f, 0.f};
    if (c4 < 25) bias = ((const float4*)agg_b)[c4];
    float4 rs = {0.f, 0.f, 0.f, 0.f};
    #pragma unroll
    for (int i = 0; i < 4; ++i) {
        rs.x += fmaxf(acc[i].x + bias.x, 0.f);
        rs.y += fmaxf(acc[i].y + bias.y, 0.f);
        rs.z += fmaxf(acc[i].z + bias.z, 0.f);
        rs.w += fmaxf(acc[i].w + bias.w, 0.f);
    }
    float* red = &ss[0][0];
    __syncthreads();
    *(float4*)&red[rg * 128 + c4 * 4] = rs;
    __syncthreads();
    if (rg == 0 && c4 < 25) {
        float4 tot = {0.f, 0.f, 0.f, 0.f};
        #pragma unroll
        for (int g = 0; g < 8; ++g) {
            float4 v = *(float4*)&red[g * 128 + c4 * 4];
            tot.x += v.x; tot.y += v.y; tot.z += v.z; tot.w += v.w;
        }
        atomicAdd(&pooled[b * A_ + c4 * 4 + 0], tot.x);
        atomicAdd(&pooled[b * A_ + c4 * 4 + 1], tot.y);
        atomicAdd(&pooled[b * A_ + c4 * 4 + 2], tot.z);
        atomicAdd(&pooled[b * A_ + c4 * 4 + 3], tot.w);
    }
}

// ---------------- K7: logits = (pooled/valid_len) @ cls^T + b
__global__ __launch_bounds__(64) void k_logits(
    const float* __restrict__ pooled, const float* __restrict__ cls_w,
    const float* __restrict__ cls_b, const int* __restrict__ mask_ids,
    float* __restrict__ out)
{
    const int tid = threadIdx.x;
    if (tid < B_ * P_) {
        const int b = tid / P_, p = tid % P_;
        int vs = 0;
        for (int l = 0; l < L_; ++l) vs += mask_ids[b * L_ + l];
        float inv = 1.0f / (float)max(vs, 1);
        float acc = cls_b[p];
        #pragma unroll 4
        for (int a = 0; a < A_; ++a) acc += (pooled[b * A_ + a] * inv) * cls_w[p * A_ + a];
        out[b * P_ + p] = acc;
    }
}

extern "C" void kernel_launch(void* const* d_in, const int* in_sizes, int n_in,
                              void* d_out, int out_size, void* d_ws, size_t ws_size,
                              hipStream_t stream) {
    const float* seq    = (const float*)d_in[0];
    const float* syn    = (const float*)d_in[1];
    const float* ln_a   = (const float*)d_in[2];
    const float* ln_b   = (const float*)d_in[3];
    const float* Wxx_w  = (const float*)d_in[4];
    const float* Wxx_b  = (const float*)d_in[5];
    const float* q_w    = (const float*)d_in[6];
    const float* q_b    = (const float*)d_in[7];
    const float* k_w    = (const float*)d_in[8];
    const float* k_b    = (const float*)d_in[9];
    const float* W_w    = (const float*)d_in[10];
    const float* W_b    = (const float*)d_in[11];
    const float* Wx_w   = (const float*)d_in[12];
    const float* Wx_b   = (const float*)d_in[13];
    const float* agg_w  = (const float*)d_in[14];
    const float* agg_b  = (const float*)d_in[15];
    const float* cls_w  = (const float*)d_in[16];
    const float* cls_b  = (const float*)d_in[17];
    const int* mask_ids = (const int*)d_in[18];
    const int* src_mask = (const int*)d_in[19];
    float* out = (float*)d_out;

    float* ws = (float*)d_ws;
    size_t off = 0;
    float* xp     = ws + off; off += (size_t)B_ * L_ * XP_;
    float* x1p    = ws + off; off += (size_t)B_ * L_ * XP_;
    float* x2p    = ws + off; off += (size_t)B_ * L_ * XP_;
    float* axb    = ws + off; off += (size_t)B_ * L_ * XP_;
    float* qt     = ws + off; off += (size_t)B_ * L_ * A_;
    float* kt     = ws + off; off += (size_t)B_ * L_ * A_;
    float* es     = ws + off; off += (size_t)B_ * H_ * L_ * L_;
    float* Vv     = ws + off; off += (size_t)B_ * L_;
    float* T      = ws + off; off += (size_t)B_ * A_;
    float* S      = ws + off; off += (size_t)B_ * A_;
    float* pooled = ws + off; off += (size_t)B_ * A_;
    float* wT     = ws + off; off += (size_t)D_ * 128;
    float* aggT   = ws + off; off += (size_t)3 * A_ * 128;
    float* qkT    = ws + off; off += (size_t)A_ * 256;
    float* WT     = ws + off; off += (size_t)A_ * 128;

    k_wprep<<<(D_ * 128) / 256, 256, 0, stream>>>(Wxx_w, wT);
    k_aggprep<<<(3 * A_ * 128) / 256, 256, 0, stream>>>(agg_w, aggT);
    k_qkprep<<<(A_ * 256) / 256, 256, 0, stream>>>(q_w, k_w, qkT);
    k_wprep2<<<(A_ * 128) / 256, 256, 0, stream>>>(W_w, WT);
    k_lnx<<<(B_ * L_) / 32, 256, 0, stream>>>(seq, ln_a, ln_b, wT, Wxx_b, xp);
    k_qkg<<<dim3((B_ * L_) / 32, 2), 256, 0, stream>>>(xp, qkT, q_b, k_b, qt, kt);
    k_attn<<<dim3(L_ / NI_, B_), 256, 0, stream>>>(qt, kt, syn, src_mask, Wx_w, es);
    k_axg<0><<<(B_ * L_) / 32, 256, 0, stream>>>(es, xp, nullptr, nullptr, nullptr, nullptr, axb);
    k_xw<<<(B_ * L_) / 32, 256, 0, stream>>>(axb, WT, W_b, x1p);
    k_extras<<<B_, 256, 0, stream>>>(x1p, Wx_w, Vv, T, S, pooled);
    k_axg<1><<<(B_ * L_) / 32, 256, 0, stream>>>(es + (size_t)L_ * L_, x1p, S, T, Vv, Wx_b, axb);
    k_xw<<<(B_ * L_) / 32, 256, 0, stream>>>(axb, WT, W_b, x2p);
    k_nodepool<<<(B_ * L_) / 32, 256, 0, stream>>>(xp, x1p, x2p, aggT, agg_b, pooled);
    k_logits<<<1, 64, 0, stream>>>(pooled, cls_w, cls_b, mask_ids, out);
}

// Round 5
// 426.771 us; speedup vs baseline: 3.5062x; 3.5062x over previous
//
#include <hip/hip_runtime.h>

#define B_ 16
#define L_ 512
#define D_ 768
#define H_ 4
#define A_ 100
#define DK_ 25
#define P_ 3
#define XP_ 128   // padded row stride for x/x1/x2/axb

// ------------------------------------------------- K0: wT[d][a] = Wxx_w[a][d], pad a to 128
__global__ __launch_bounds__(256) void k_wprep(const float* __restrict__ Wxx_w,
                                               float* __restrict__ wT)
{
    const int idx = blockIdx.x * 256 + threadIdx.x;     // 768*128
    const int d = idx >> 7, a = idx & 127;
    wT[idx] = (a < A_) ? Wxx_w[(size_t)a * D_ + d] : 0.f;
}

// ------------------------------------- K0b: aggT[c][k][n] = agg_w[n][c*100+k], pad n to 128
__global__ __launch_bounds__(256) void k_aggprep(const float* __restrict__ agg_w,
                                                 float* __restrict__ aggT)
{
    const int idx = blockIdx.x * 256 + threadIdx.x;     // 3*100*128 = 38400
    const int n = idx & 127, k = (idx >> 7) % A_, c = idx / (128 * A_);
    aggT[idx] = (n < A_) ? agg_w[(size_t)n * (3 * A_) + c * A_ + k] : 0.f;
}

// ------------------------------------- K0c: qkT[k][n]: n<128 -> q_w[n][k], n>=128 -> k_w[n-128][k]
__global__ __launch_bounds__(256) void k_qkprep(const float* __restrict__ q_w,
                                                const float* __restrict__ k_w,
                                                float* __restrict__ qkT)
{
    const int idx = blockIdx.x * 256 + threadIdx.x;     // 100*256 = 25600
    const int n = idx & 255, k = idx >> 8;
    const int half = n >> 7, a = n & 127;
    const float* w = half ? k_w : q_w;
    qkT[idx] = (a < A_) ? w[(size_t)a * A_ + k] : 0.f;
}

// ------------------------------------- K0d: WT[k][n] = W_w[n][k], pad n to 128
__global__ __launch_bounds__(256) void k_wprep2(const float* __restrict__ W_w,
                                                float* __restrict__ WT)
{
    const int idx = blockIdx.x * 256 + threadIdx.x;     // 100*128 = 12800
    const int n = idx & 127, k = idx >> 7;
    WT[idx] = (n < A_) ? W_w[(size_t)n * A_ + k] : 0.f;
}

// ------------------- K1: fused LayerNorm + x = seq_ln @ Wxx^T + b  (tiled GEMM)
// output xp: (B*L, 128), cols 100..127 zero.
__global__ __launch_bounds__(256) void k_lnx(
    const float* __restrict__ seq, const float* __restrict__ ln_a, const float* __restrict__ ln_b,
    const float* __restrict__ wT, const float* __restrict__ Wxx_b, float* __restrict__ xp)
{
    __shared__ float ss[32][36];
    __shared__ float ws[32][128];
    __shared__ float mean_s[32], rd_s[32];
    const int tid = threadIdx.x;
    const int row0 = blockIdx.x * 32;
    const int wv = tid >> 6, lane = tid & 63;

    for (int rr = 0; rr < 8; ++rr) {
        const int r = wv * 8 + rr;
        const float4* src = (const float4*)(seq + (size_t)(row0 + r) * D_);
        float4 a = src[lane], b = src[lane + 64], c = src[lane + 128];
        float s = a.x + a.y + a.z + a.w + b.x + b.y + b.z + b.w + c.x + c.y + c.z + c.w;
        #pragma unroll
        for (int o = 32; o; o >>= 1) s += __shfl_xor(s, o);
        const float m = s * (1.0f / 768.0f);
        float q = (a.x-m)*(a.x-m) + (a.y-m)*(a.y-m) + (a.z-m)*(a.z-m) + (a.w-m)*(a.w-m)
                + (b.x-m)*(b.x-m) + (b.y-m)*(b.y-m) + (b.z-m)*(b.z-m) + (b.w-m)*(b.w-m)
                + (c.x-m)*(c.x-m) + (c.y-m)*(c.y-m) + (c.z-m)*(c.z-m) + (c.w-m)*(c.w-m);
        #pragma unroll
        for (int o = 32; o; o >>= 1) q += __shfl_xor(q, o);
        if (lane == 0) {
            mean_s[r] = m;
            rd_s[r] = 1.0f / (sqrtf(q * (1.0f / 767.0f)) + 1e-6f);
        }
    }
    __syncthreads();

    const int c4 = tid & 31, rg = tid >> 5;
    float4 acc[4];
    #pragma unroll
    for (int i = 0; i < 4; ++i) { acc[i].x = acc[i].y = acc[i].z = acc[i].w = 0.f; }

    for (int kc = 0; kc < 24; ++kc) {
        {
            const int r = tid >> 3, k4 = tid & 7;
            float4 v = *(const float4*)(seq + (size_t)(row0 + r) * D_ + kc * 32 + k4 * 4);
            float4 la = ((const float4*)ln_a)[kc * 8 + k4];
            float4 lb = ((const float4*)ln_b)[kc * 8 + k4];
            const float m = mean_s[r], rd = rd_s[r];
            float4 o;
            o.x = la.x * ((v.x - m) * rd) + lb.x;
            o.y = la.y * ((v.y - m) * rd) + lb.y;
            o.z = la.z * ((v.z - m) * rd) + lb.z;
            o.w = la.w * ((v.w - m) * rd) + lb.w;
            *(float4*)&ss[r][k4 * 4] = o;
        }
        #pragma unroll
        for (int t = 0; t < 4; ++t) {
            const int idx = tid + t * 256;
            const int k = idx >> 5, cc = idx & 31;
            *(float4*)&ws[k][cc * 4] = *(const float4*)(wT + (size_t)(kc * 32 + k) * 128 + cc * 4);
        }
        __syncthreads();
        #pragma unroll 2
        for (int k = 0; k < 32; k += 4) {
            float4 sv[4];
            #pragma unroll
            for (int i = 0; i < 4; ++i) sv[i] = *(float4*)&ss[rg * 4 + i][k];
            #pragma unroll
            for (int j = 0; j < 4; ++j) {
                float4 w4 = *(float4*)&ws[k + j][c4 * 4];
                #pragma unroll
                for (int i = 0; i < 4; ++i) {
                    const float sj = ((float*)&sv[i])[j];
                    acc[i].x += sj * w4.x; acc[i].y += sj * w4.y;
                    acc[i].z += sj * w4.z; acc[i].w += sj * w4.w;
                }
            }
        }
        __syncthreads();
    }

    float4 bias = {0.f, 0.f, 0.f, 0.f};
    if (c4 < 25) bias = ((const float4*)Wxx_b)[c4];
    #pragma unroll
    for (int i = 0; i < 4; ++i) {
        float4 o;
        o.x = acc[i].x + bias.x; o.y = acc[i].y + bias.y;
        o.z = acc[i].z + bias.z; o.w = acc[i].w + bias.w;
        *(float4*)(xp + (size_t)(row0 + rg * 4 + i) * XP_ + c4 * 4) = o;   // pad cols stay 0 (wT padded)
    }
}

// ------------------- K2: q/k = x @ [q_w|k_w]^T + bias  (tiled GEMM); qt/kt (B,L,100)
__global__ __launch_bounds__(256) void k_qkg(
    const float* __restrict__ xp, const float* __restrict__ qkT,
    const float* __restrict__ q_b, const float* __restrict__ k_b,
    float* __restrict__ qt, float* __restrict__ kt)
{
    __shared__ float ss[32][104];
    __shared__ float ws[A_][128];
    const int tid = threadIdx.x;
    const int row0 = blockIdx.x * 32;
    const int half = blockIdx.y;
    const int c4 = tid & 31, rg = tid >> 5;

    for (int idx = tid; idx < 32 * 25; idx += 256) {
        const int r = idx / 25, k4 = idx % 25;
        *(float4*)&ss[r][k4 * 4] = *(const float4*)(xp + (size_t)(row0 + r) * XP_ + k4 * 4);
    }
    for (int idx = tid; idx < A_ * 32; idx += 256) {
        const int k = idx >> 5, cc = idx & 31;
        *(float4*)&ws[k][cc * 4] = *(const float4*)(qkT + (size_t)k * 256 + half * 128 + cc * 4);
    }
    __syncthreads();

    float4 acc[4];
    #pragma unroll
    for (int i = 0; i < 4; ++i) { acc[i].x = acc[i].y = acc[i].z = acc[i].w = 0.f; }
    #pragma unroll 5
    for (int k = 0; k < A_; k += 4) {
        float4 sv[4];
        #pragma unroll
        for (int i = 0; i < 4; ++i) sv[i] = *(float4*)&ss[rg * 4 + i][k];
        #pragma unroll
        for (int j = 0; j < 4; ++j) {
            float4 w4 = *(float4*)&ws[k + j][c4 * 4];
            #pragma unroll
            for (int i = 0; i < 4; ++i) {
                const float sj = ((float*)&sv[i])[j];
                acc[i].x += sj * w4.x; acc[i].y += sj * w4.y;
                acc[i].z += sj * w4.z; acc[i].w += sj * w4.w;
            }
        }
    }

    if (c4 < 25) {
        const float4 bias = ((const float4*)(half ? k_b : q_b))[c4];
        float* dst = half ? kt : qt;
        #pragma unroll
        for (int i = 0; i < 4; ++i) {
            float4 o;
            o.x = acc[i].x + bias.x; o.y = acc[i].y + bias.y;
            o.z = acc[i].z + bias.z; o.w = acc[i].w + bias.w;
            *(float4*)(dst + (size_t)(row0 + rg * 4 + i) * A_ + c4 * 4) = o;
        }
    }
}

// --------------- K3 (fused v3): scores + softmax + h-combine, TWO-PASS ONLINE RECOMPUTE.
// Writes ONLY es plane (b,0) = sum_h adj[h] and plane (b,1) = sum_h cs[h]*adj[h].
// Key property vs v1/v2: NO register array is indexed by the K-tile loop variable t,
// so nothing can fall into scratch even if the (barrier-containing) t-loop stays rolled.
// Pass 1: per tile, fold 8 scores/lane (4h x 2 rows) into online (mrun,srun)[4][2].
// Cross-lane shfl merge. Pass 2: re-stage tiles, recompute scores, p=exp(s-m)*inv,
// fold into e0/e1 and store. K tile in LDS stride 101 (bank = 5*lane mod 32, clean).
#define NI_ 8
__global__ __launch_bounds__(256) void k_attn(
    const float* __restrict__ qt, const float* __restrict__ kt,
    const float* __restrict__ syn, const int* __restrict__ src_mask,
    const float* __restrict__ Wx_w, float* __restrict__ es)
{
    __shared__ __align__(16) float ks[64 * 101];        // 25856 B
    __shared__ __align__(16) float qs[NI_ * 4 * 28];    // [i][h][d], 3584 B
    __shared__ float cs[4];

    const int tid = threadIdx.x;
    const int b = blockIdx.y;
    const int i0 = blockIdx.x * NI_;
    const int wv = tid >> 6, lane = tid & 63;

    // stage q fragments: qs[(i*4+h)*28 + d]
    for (int idx = tid; idx < NI_ * 4 * 25; idx += 256) {
        const int i = idx / 100, rem = idx % 100;
        const int h = rem / 25, d = rem % 25;
        qs[(i * 4 + h) * 28 + d] = qt[(size_t)(b * L_ + i0 + i) * A_ + h * DK_ + d];
    }
    if (tid < 4) cs[tid] = Wx_w[tid] + Wx_w[204 + tid] + Wx_w[408 + tid] + Wx_w[612 + tid];

    const float* q0b = qs + (size_t)(wv * 2 + 0) * 4 * 28;
    const float* q1b = qs + (size_t)(wv * 2 + 1) * 4 * 28;

    float mrun[4][2], srun[4][2];
    #pragma unroll
    for (int h = 0; h < 4; ++h)
        #pragma unroll
        for (int il = 0; il < 2; ++il) { mrun[h][il] = -3.0e38f; srun[h][il] = 0.f; }

    // ---------------- pass 1: online max / sum ----------------
    for (int t = 0; t < 8; ++t) {
        __syncthreads();    // t=0: qs/cs staged; t>0: prev tile reads done
        for (int idx = tid; idx < 64 * 25; idx += 256) {
            const int r = idx / 25, c = idx % 25;
            const float4 v = *(const float4*)(kt + (size_t)(b * L_ + t * 64 + r) * A_ + c * 4);
            float* dst = ks + r * 101 + c * 4;
            dst[0] = v.x; dst[1] = v.y; dst[2] = v.z; dst[3] = v.w;
        }
        __syncthreads();
        const int mk = src_mask[b * L_ + t * 64 + lane];
        const float* kr = ks + lane * 101;
        #pragma unroll
        for (int h = 0; h < 4; ++h) {
            const float* kh = kr + h * DK_;
            const float* qa_ = q0b + h * 28;
            const float* qb_ = q1b + h * 28;
            float a0 = 0.f, a1 = 0.f;
            #pragma unroll
            for (int d4 = 0; d4 < 6; ++d4) {
                const float k0 = kh[d4*4+0], k1 = kh[d4*4+1], k2 = kh[d4*4+2], k3 = kh[d4*4+3];
                const float4 qa = *(const float4*)&qa_[d4 * 4];
                const float4 qb = *(const float4*)&qb_[d4 * 4];
                a0 += qa.x*k0 + qa.y*k1 + qa.z*k2 + qa.w*k3;
                a1 += qb.x*k0 + qb.y*k1 + qb.z*k2 + qb.w*k3;
            }
            { const float kk = kh[24]; a0 += qa_[24]*kk; a1 += qb_[24]*kk; }
            #pragma unroll
            for (int il = 0; il < 2; ++il) {
                const float a = il ? a1 : a0;
                const int ig = i0 + wv * 2 + il;
                const float sy = syn[((size_t)(b * H_ + h) * L_ + ig) * L_ + t * 64 + lane];
                const float s = (mk ? a * 0.2f : -1e9f) + sy;
                const float mo = mrun[h][il];
                const float mn = fmaxf(mo, s);
                srun[h][il] = srun[h][il] * __expf(mo - mn) + __expf(s - mn);
                mrun[h][il] = mn;
            }
        }
    }

    // ---------------- cross-lane (m,sum) merge ----------------
    #pragma unroll
    for (int h = 0; h < 4; ++h)
        #pragma unroll
        for (int il = 0; il < 2; ++il) {
            float m = mrun[h][il], su = srun[h][il];
            #pragma unroll
            for (int o = 32; o; o >>= 1) {
                const float mo = __shfl_xor(m, o);
                const float so = __shfl_xor(su, o);
                const float mn = fmaxf(m, mo);
                su = su * __expf(m - mn) + so * __expf(mo - mn);
                m = mn;
            }
            mrun[h][il] = m;
            srun[h][il] = 1.0f / su;    // now inv-sum
        }

    const float c0 = cs[0], c1 = cs[1], c2 = cs[2], c3 = cs[3];

    // ---------------- pass 2: recompute, normalize, combine, write ----------------
    for (int t = 0; t < 8; ++t) {
        __syncthreads();    // pass-1 reads of ks are done
        for (int idx = tid; idx < 64 * 25; idx += 256) {
            const int r = idx / 25, c = idx % 25;
            const float4 v = *(const float4*)(kt + (size_t)(b * L_ + t * 64 + r) * A_ + c * 4);
            float* dst = ks + r * 101 + c * 4;
            dst[0] = v.x; dst[1] = v.y; dst[2] = v.z; dst[3] = v.w;
        }
        __syncthreads();
        const int mk = src_mask[b * L_ + t * 64 + lane];
        const float* kr = ks + lane * 101;
        float e00 = 0.f, e10 = 0.f;   // il=0: plane0, plane1
        float e01 = 0.f, e11 = 0.f;   // il=1
        #pragma unroll
        for (int h = 0; h < 4; ++h) {
            const float* kh = kr + h * DK_;
            const float* qa_ = q0b + h * 28;
            const float* qb_ = q1b + h * 28;
            float a0 = 0.f, a1 = 0.f;
            #pragma unroll
            for (int d4 = 0; d4 < 6; ++d4) {
                const float k0 = kh[d4*4+0], k1 = kh[d4*4+1], k2 = kh[d4*4+2], k3 = kh[d4*4+3];
                const float4 qa = *(const float4*)&qa_[d4 * 4];
                const float4 qb = *(const float4*)&qb_[d4 * 4];
                a0 += qa.x*k0 + qa.y*k1 + qa.z*k2 + qa.w*k3;
                a1 += qb.x*k0 + qb.y*k1 + qb.z*k2 + qb.w*k3;
            }
            { const float kk = kh[24]; a0 += qa_[24]*kk; a1 += qb_[24]*kk; }
            const float ch = (h == 0) ? c0 : (h == 1) ? c1 : (h == 2) ? c2 : c3;
            #pragma unroll
            for (int il = 0; il < 2; ++il) {
                const float a = il ? a1 : a0;
                const int ig = i0 + wv * 2 + il;
                const float sy = syn[((size_t)(b * H_ + h) * L_ + ig) * L_ + t * 64 + lane];
                const float s = (mk ? a * 0.2f : -1e9f) + sy;
                const float p = __expf(s - mrun[h][il]) * srun[h][il];
                if (il) { e01 += p; e11 += ch * p; }
                else    { e00 += p; e10 += ch * p; }
            }
        }
        {
            const int ig = i0 + wv * 2;
            es[((size_t)(b * H_ + 0) * L_ + ig) * L_ + t * 64 + lane] = e00;
            es[((size_t)(b * H_ + 1) * L_ + ig) * L_ + t * 64 + lane] = e10;
            es[((size_t)(b * H_ + 0) * L_ + ig + 1) * L_ + t * 64 + lane] = e01;
            es[((size_t)(b * H_ + 1) * L_ + ig + 1) * L_ + t * 64 + lane] = e11;
        }
    }
}

// ------------- K4a: axb = (adj @ x)/H [+ extras]   (tiled GEMM, 32 rows x 128 cols, K=512)
template<int LAYER2>
__global__ __launch_bounds__(256) void k_axg(
    const float* __restrict__ adj, const float* __restrict__ xp,
    const float* __restrict__ S, const float* __restrict__ T,
    const float* __restrict__ Vv, const float* __restrict__ Wx_b,
    float* __restrict__ axb)
{
    __shared__ float ss[32][36];
    __shared__ float ws[32][128];
    const int tid = threadIdx.x;
    const int row0 = blockIdx.x * 32;       // global row in [0, B*L)
    const int b = row0 >> 9, i0 = row0 & 511;
    const float* adjb = adj + (size_t)b * 4 * L_ * L_;
    const int c4 = tid & 31, rg = tid >> 5;
    float4 acc[4];
    #pragma unroll
    for (int i = 0; i < 4; ++i) { acc[i].x = acc[i].y = acc[i].z = acc[i].w = 0.f; }

    for (int kc = 0; kc < 16; ++kc) {
        {
            const int r = tid >> 3, q4 = tid & 7;
            *(float4*)&ss[r][q4 * 4] =
                *(const float4*)(adjb + (size_t)(i0 + r) * L_ + kc * 32 + q4 * 4);
        }
        #pragma unroll
        for (int t = 0; t < 4; ++t) {
            const int idx = tid + t * 256;
            const int k = idx >> 5, cc = idx & 31;
            *(float4*)&ws[k][cc * 4] =
                *(const float4*)(xp + ((size_t)b * L_ + kc * 32 + k) * XP_ + cc * 4);
        }
        __syncthreads();
        #pragma unroll 2
        for (int k = 0; k < 32; k += 4) {
            float4 sv[4];
            #pragma unroll
            for (int i = 0; i < 4; ++i) sv[i] = *(float4*)&ss[rg * 4 + i][k];
            #pragma unroll
            for (int j = 0; j < 4; ++j) {
                float4 w4 = *(float4*)&ws[k + j][c4 * 4];
                #pragma unroll
                for (int i = 0; i < 4; ++i) {
                    const float sj = ((float*)&sv[i])[j];
                    acc[i].x += sj * w4.x; acc[i].y += sj * w4.y;
                    acc[i].z += sj * w4.z; acc[i].w += sj * w4.w;
                }
            }
        }
        __syncthreads();
    }

    float wb = 0.f;
    float4 Sv = {0.f, 0.f, 0.f, 0.f}, Tv = {0.f, 0.f, 0.f, 0.f};
    if (LAYER2) {
        wb = Wx_b[0] + Wx_b[1] + Wx_b[2] + Wx_b[3];
        if (c4 < 25) {
            Sv = ((const float4*)(S + b * A_))[c4];
            Tv = ((const float4*)(T + b * A_))[c4];
        }
    }
    #pragma unroll
    for (int i = 0; i < 4; ++i) {
        const int grow = row0 + rg * 4 + i;
        const float vv = LAYER2 ? (Vv[grow] + wb) : 0.f;
        float4 o;
        o.x = (acc[i].x + Sv.x + vv * Tv.x) * 0.25f;
        o.y = (acc[i].y + Sv.y + vv * Tv.y) * 0.25f;
        o.z = (acc[i].z + Sv.z + vv * Tv.z) * 0.25f;
        o.w = (acc[i].w + Sv.w + vv * Tv.w) * 0.25f;
        *(float4*)(axb + (size_t)grow * XP_ + c4 * 4) = o;   // pad cols -> 0
    }
}

// ------------- K4b: xout = relu(axb @ W^T + b)   (tiled GEMM, K=100)
__global__ __launch_bounds__(256) void k_xw(
    const float* __restrict__ axb, const float* __restrict__ WT,
    const float* __restrict__ W_b, float* __restrict__ xout)
{
    __shared__ float ss[32][104];
    __shared__ float ws[A_][128];
    const int tid = threadIdx.x;
    const int row0 = blockIdx.x * 32;
    const int c4 = tid & 31, rg = tid >> 5;

    for (int idx = tid; idx < 32 * 25; idx += 256) {
        const int r = idx / 25, k4 = idx % 25;
        *(float4*)&ss[r][k4 * 4] = *(const float4*)(axb + (size_t)(row0 + r) * XP_ + k4 * 4);
    }
    for (int idx = tid; idx < A_ * 32; idx += 256) {
        const int k = idx >> 5, cc = idx & 31;
        *(float4*)&ws[k][cc * 4] = *(const float4*)(WT + (size_t)k * 128 + cc * 4);
    }
    __syncthreads();

    float4 acc[4];
    #pragma unroll
    for (int i = 0; i < 4; ++i) { acc[i].x = acc[i].y = acc[i].z = acc[i].w = 0.f; }
    #pragma unroll 5
    for (int k = 0; k < A_; k += 4) {
        float4 sv[4];
        #pragma unroll
        for (int i = 0; i < 4; ++i) sv[i] = *(float4*)&ss[rg * 4 + i][k];
        #pragma unroll
        for (int j = 0; j < 4; ++j) {
            float4 w4 = *(float4*)&ws[k + j][c4 * 4];
            #pragma unroll
            for (int i = 0; i < 4; ++i) {
                const float sj = ((float*)&sv[i])[j];
                acc[i].x += sj * w4.x; acc[i].y += sj * w4.y;
                acc[i].z += sj * w4.z; acc[i].w += sj * w4.w;
            }
        }
    }

    float4 bias = {0.f, 0.f, 0.f, 0.f};
    if (c4 < 25) bias = ((const float4*)W_b)[c4];
    #pragma unroll
    for (int i = 0; i < 4; ++i) {
        float4 o;
        o.x = fmaxf(acc[i].x + bias.x, 0.f); o.y = fmaxf(acc[i].y + bias.y, 0.f);
        o.z = fmaxf(acc[i].z + bias.z, 0.f); o.w = fmaxf(acc[i].w + bias.w, 0.f);
        *(float4*)(xout + (size_t)(row0 + rg * 4 + i) * XP_ + c4 * 4) = o;  // WT pad -> 0
    }
}

// ---------------- K5: rank-1 extras for layer 2: Vv (B,L), T,S (B,A); zero pooled
__global__ __launch_bounds__(256) void k_extras(
    const float* __restrict__ x1, const float* __restrict__ Wx_w,
    float* __restrict__ Vv, float* __restrict__ T, float* __restrict__ S,
    float* __restrict__ pooled)
{
    __shared__ float b1s[A_], b2s[A_], Ul[L_];
    const int tid = threadIdx.x, b = blockIdx.x;
    if (tid < A_) {
        float s1 = 0.f, s2 = 0.f;
        #pragma unroll
        for (int g = 0; g < H_; ++g) {
            s1 += Wx_w[g * 204 + 4 + tid];
            s2 += Wx_w[g * 204 + 104 + tid];
        }
        b1s[tid] = s1; b2s[tid] = s2;
        pooled[b * A_ + tid] = 0.f;
    }
    __syncthreads();
    for (int j = tid; j < L_; j += 256) {
        const float* xr = x1 + ((size_t)b * L_ + j) * XP_;
        float u = 0.f, v = 0.f;
        #pragma unroll 4
        for (int c = 0; c < A_; ++c) { float xv = xr[c]; u += xv * b1s[c]; v += xv * b2s[c]; }
        Ul[j] = u;
        Vv[b * L_ + j] = v;
    }
    __syncthreads();
    if (tid < A_) {
        float t = 0.f, s = 0.f;
        for (int j = 0; j < L_; ++j) {
            float xv = x1[((size_t)b * L_ + j) * XP_ + tid];
            t += xv; s += Ul[j] * xv;
        }
        T[b * A_ + tid] = t; S[b * A_ + tid] = s;
    }
}

// ---------------- K6: pooled[b] += sum_rows relu([x,x1,x2]@agg^T + b)   (tiled GEMM)
__global__ __launch_bounds__(256) void k_nodepool(
    const float* __restrict__ x, const float* __restrict__ x1, const float* __restrict__ x2,
    const float* __restrict__ aggT, const float* __restrict__ agg_b,
    float* __restrict__ pooled)
{
    __shared__ float ss[32][104];
    __shared__ float ws[A_][128];
    const int tid = threadIdx.x;
    const int row0 = blockIdx.x * 32;
    const int b = row0 >> 9;
    const int c4 = tid & 31, rg = tid >> 5;
    float4 acc[4];
    #pragma unroll
    for (int i = 0; i < 4; ++i) { acc[i].x = acc[i].y = acc[i].z = acc[i].w = 0.f; }

    for (int c = 0; c < 3; ++c) {
        const float* src = (c == 0) ? x : (c == 1) ? x1 : x2;
        for (int idx = tid; idx < 32 * 25; idx += 256) {
            const int r = idx / 25, k4 = idx % 25;
            *(float4*)&ss[r][k4 * 4] =
                *(const float4*)(src + (size_t)(row0 + r) * XP_ + k4 * 4);
        }
        for (int idx = tid; idx < A_ * 32; idx += 256) {
            const int k = idx >> 5, cc = idx & 31;
            *(float4*)&ws[k][cc * 4] =
                *(const float4*)(aggT + ((size_t)c * A_ + k) * 128 + cc * 4);
        }
        __syncthreads();
        #pragma unroll 5
        for (int k = 0; k < A_; k += 4) {
            float4 sv[4];
            #pragma unroll
            for (int i = 0; i < 4; ++i) sv[i] = *(float4*)&ss[rg * 4 + i][k];
            #pragma unroll
            for (int j = 0; j < 4; ++j) {
                float4 w4 = *(float4*)&ws[k + j][c4 * 4];
                #pragma unroll
                for (int i = 0; i < 4; ++i) {
                    const float sj = ((float*)&sv[i])[j];
                    acc[i].x += sj * w4.x; acc[i].y += sj * w4.y;
                    acc[i].z += sj * w4.z; acc[i].w += sj * w4.w;
                }
            }
        }
        __syncthreads();
    }

    float4 bias = {0.f, 0.f, 0.f, 0.f};
    if (c4 < 25) bias = ((const float4*)agg_b)[c4];
    float4 rs = {0.f, 0.f, 0.f, 0.f};
    #pragma unroll
    for (int i = 0; i < 4; ++i) {
        rs.x += fmaxf(acc[i].x + bias.x, 0.f);
        rs.y += fmaxf(acc[i].y + bias.y, 0.f);
        rs.z += fmaxf(acc[i].z + bias.z, 0.f);
        rs.w += fmaxf(acc[i].w + bias.w, 0.f);
    }
    float* red = &ss[0][0];
    __syncthreads();
    *(float4*)&red[rg * 128 + c4 * 4] = rs;
    __syncthreads();
    if (rg == 0 && c4 < 25) {
        float4 tot = {0.f, 0.f, 0.f, 0.f};
        #pragma unroll
        for (int g = 0; g < 8; ++g) {
            float4 v = *(float4*)&red[g * 128 + c4 * 4];
            tot.x += v.x; tot.y += v.y; tot.z += v.z; tot.w += v.w;
        }
        atomicAdd(&pooled[b * A_ + c4 * 4 + 0], tot.x);
        atomicAdd(&pooled[b * A_ + c4 * 4 + 1], tot.y);
        atomicAdd(&pooled[b * A_ + c4 * 4 + 2], tot.z);
        atomicAdd(&pooled[b * A_ + c4 * 4 + 3], tot.w);
    }
}

// ---------------- K7: logits = (pooled/valid_len) @ cls^T + b
__global__ __launch_bounds__(64) void k_logits(
    const float* __restrict__ pooled, const float* __restrict__ cls_w,
    const float* __restrict__ cls_b, const int* __restrict__ mask_ids,
    float* __restrict__ out)
{
    const int tid = threadIdx.x;
    if (tid < B_ * P_) {
        const int b = tid / P_, p = tid % P_;
        int vs = 0;
        for (int l = 0; l < L_; ++l) vs += mask_ids[b * L_ + l];
        float inv = 1.0f / (float)max(vs, 1);
        float acc = cls_b[p];
        #pragma unroll 4
        for (int a = 0; a < A_; ++a) acc += (pooled[b * A_ + a] * inv) * cls_w[p * A_ + a];
        out[b * P_ + p] = acc;
    }
}

extern "C" void kernel_launch(void* const* d_in, const int* in_sizes, int n_in,
                              void* d_out, int out_size, void* d_ws, size_t ws_size,
                              hipStream_t stream) {
    const float* seq    = (const float*)d_in[0];
    const float* syn    = (const float*)d_in[1];
    const float* ln_a   = (const float*)d_in[2];
    const float* ln_b   = (const float*)d_in[3];
    const float* Wxx_w  = (const float*)d_in[4];
    const float* Wxx_b  = (const float*)d_in[5];
    const float* q_w    = (const float*)d_in[6];
    const float* q_b    = (const float*)d_in[7];
    const float* k_w    = (const float*)d_in[8];
    const float* k_b    = (const float*)d_in[9];
    const float* W_w    = (const float*)d_in[10];
    const float* W_b    = (const float*)d_in[11];
    const float* Wx_w   = (const float*)d_in[12];
    const float* Wx_b   = (const float*)d_in[13];
    const float* agg_w  = (const float*)d_in[14];
    const float* agg_b  = (const float*)d_in[15];
    const float* cls_w  = (const float*)d_in[16];
    const float* cls_b  = (const float*)d_in[17];
    const int* mask_ids = (const int*)d_in[18];
    const int* src_mask = (const int*)d_in[19];
    float* out = (float*)d_out;

    float* ws = (float*)d_ws;
    size_t off = 0;
    float* xp     = ws + off; off += (size_t)B_ * L_ * XP_;
    float* x1p    = ws + off; off += (size_t)B_ * L_ * XP_;
    float* x2p    = ws + off; off += (size_t)B_ * L_ * XP_;
    float* axb    = ws + off; off += (size_t)B_ * L_ * XP_;
    float* qt     = ws + off; off += (size_t)B_ * L_ * A_;
    float* kt     = ws + off; off += (size_t)B_ * L_ * A_;
    float* es     = ws + off; off += (size_t)B_ * H_ * L_ * L_;
    float* Vv     = ws + off; off += (size_t)B_ * L_;
    float* T      = ws + off; off += (size_t)B_ * A_;
    float* S      = ws + off; off += (size_t)B_ * A_;
    float* pooled = ws + off; off += (size_t)B_ * A_;
    float* wT     = ws + off; off += (size_t)D_ * 128;
    float* aggT   = ws + off; off += (size_t)3 * A_ * 128;
    float* qkT    = ws + off; off += (size_t)A_ * 256;
    float* WT     = ws + off; off += (size_t)A_ * 128;

    k_wprep<<<(D_ * 128) / 256, 256, 0, stream>>>(Wxx_w, wT);
    k_aggprep<<<(3 * A_ * 128) / 256, 256, 0, stream>>>(agg_w, aggT);
    k_qkprep<<<(A_ * 256) / 256, 256, 0, stream>>>(q_w, k_w, qkT);
    k_wprep2<<<(A_ * 128) / 256, 256, 0, stream>>>(W_w, WT);
    k_lnx<<<(B_ * L_) / 32, 256, 0, stream>>>(seq, ln_a, ln_b, wT, Wxx_b, xp);
    k_qkg<<<dim3((B_ * L_) / 32, 2), 256, 0, stream>>>(xp, qkT, q_b, k_b, qt, kt);
    k_attn<<<dim3(L_ / NI_, B_), 256, 0, stream>>>(qt, kt, syn, src_mask, Wx_w, es);
    k_axg<0><<<(B_ * L_) / 32, 256, 0, stream>>>(es, xp, nullptr, nullptr, nullptr, nullptr, axb);
    k_xw<<<(B_ * L_) / 32, 256, 0, stream>>>(axb, WT, W_b, x1p);
    k_extras<<<B_, 256, 0, stream>>>(x1p, Wx_w, Vv, T, S, pooled);
    k_axg<1><<<(B_ * L_) / 32, 256, 0, stream>>>(es + (size_t)L_ * L_, x1p, S, T, Vv, Wx_b, axb);
    k_xw<<<(B_ * L_) / 32, 256, 0, stream>>>(axb, WT, W_b, x2p);
    k_nodepool<<<(B_ * L_) / 32, 256, 0, stream>>>(xp, x1p, x2p, aggT, agg_b, pooled);
    k_logits<<<1, 64, 0, stream>>>(pooled, cls_w, cls_b, mask_ids, out);
}